// Round 9
// baseline (163.778 us; speedup 1.0000x reference)
//
#include <hip/hip_runtime.h>

#define T 8192
#define BATCH 512
#define NTH 1024
#define EPT 8
#define NW 16

typedef float nfloat4 __attribute__((ext_vector_type(4)));

template <int N>
__device__ __forceinline__ void block_reduce(float (&v)[N], float* s_red, float* s_bc) {
    int lane = threadIdx.x & 63, wid = threadIdx.x >> 6;
#pragma unroll
    for (int j = 0; j < N; j++) {
        float x = v[j];
#pragma unroll
        for (int off = 32; off; off >>= 1) x += __shfl_xor(x, off);
        if (lane == 0) s_red[wid * N + j] = x;
    }
    __syncthreads();
    if (threadIdx.x < N) {
        float s = 0.f;
#pragma unroll
        for (int w = 0; w < NW; w++) s += s_red[w * N + threadIdx.x];
        s_bc[threadIdx.x] = s;
    }
    __syncthreads();
}

__global__ __launch_bounds__(NTH) void teacher_kernel(
    const float* __restrict__ dur, const float* __restrict__ stats,
    const float* __restrict__ trace, const float* __restrict__ mask,
    const float* __restrict__ cue, float* __restrict__ out)
{
    const int row = blockIdx.x;
    const int tid = threadIdx.x;
    const int lane = tid & 63, wid = tid >> 6;
    const int base = tid * EPT;

    __shared__ unsigned s_hist[2 * NW * 256];   // 32 KB ping-pong
    __shared__ float s_v[NTH * EPT + 2];        // 32 KB raw speech scores, padded
    __shared__ float s_red[NW * 13];
    __shared__ float s_bc[16];
    __shared__ float s_c0[NTH];                 // each thread's cue[base]
    __shared__ float s_ws[NW];
    __shared__ unsigned s_sel[4];
    __shared__ unsigned s_wu[NW];

    const size_t BT = (size_t)BATCH * T;
    const size_t rbase = (size_t)row * T;

    const float4* m4 = (const float4*)(mask + rbase);
    const float4* d4 = (const float4*)(dur + rbase);
    const float4* c4 = (const float4*)(cue + rbase);
    const float4* t4 = (const float4*)(trace + rbase * 4);

    float* o_sb  = out + 2 * BT;
    float* o_pb  = out + 2 * BT + BATCH;
    float* o_cf  = out + 3 * BT + 2 * BATCH;
    nfloat4* spe4 = (nfloat4*)(out + rbase);
    nfloat4* pae4 = (nfloat4*)(out + BT + rbase);
    nfloat4* al4  = (nfloat4*)(out + 2 * BT + 2 * BATCH + rbase);
    nfloat4* tc4  = ((nfloat4*)(out + 3 * BT + 3 * BATCH)) + rbase;
    nfloat4* pc4  = (nfloat4*)(out + 7 * BT + 3 * BATCH + rbase);
    nfloat4* bk4  = (nfloat4*)(out + 8 * BT + 3 * BATCH + rbase);

    float acc[12];
#pragma unroll
    for (int j = 0; j < 12; j++) acc[j] = 0.f;
    float statmax = (tid < BATCH) ? fminf(fmaxf(stats[tid * 5 + 4], 0.f), 1.f) : 0.f;

    // ---- Phase 1: full input read, trace_ctx write, 12 masked sums + stats max
#define P1(jj, M_, D_, C_, TR_) {                                              \
        float m_ = (M_), d_ = (D_), c_ = (C_); float4 tr_ = (TR_);             \
        nfloat4 tcv = {tr_.x * m_, tr_.y * m_, tr_.z * m_, tr_.w * m_};        \
        __builtin_nontemporal_store(tcv, &tc4[base + (jj)]);                   \
        acc[0] += m_;              acc[1] += d_ * m_;                          \
        acc[2] += tr_.x * m_;      acc[3] += tr_.x * tr_.x * m_;               \
        acc[4] += tr_.y * m_;      acc[5] += tr_.y * tr_.y * m_;               \
        acc[6] += tr_.z * m_;      acc[7] += tr_.z * tr_.z * m_;               \
        acc[8] += tr_.w * m_;      acc[9] += tr_.w * tr_.w * m_;               \
        acc[10] += c_ * m_;        acc[11] += c_ * tr_.z * m_; }
    {
        float4 mm = m4[tid * 2], dd = d4[tid * 2], cc = c4[tid * 2];
        float4 t0 = t4[base + 0], t1 = t4[base + 1], t2 = t4[base + 2], t3 = t4[base + 3];
        s_c0[tid] = cc.x;
        P1(0, mm.x, dd.x, cc.x, t0);
        P1(1, mm.y, dd.y, cc.y, t1);
        P1(2, mm.z, dd.z, cc.z, t2);
        P1(3, mm.w, dd.w, cc.w, t3);
    }
    {
        float4 mm = m4[tid * 2 + 1], dd = d4[tid * 2 + 1], cc = c4[tid * 2 + 1];
        float4 t0 = t4[base + 4], t1 = t4[base + 5], t2 = t4[base + 6], t3 = t4[base + 7];
        P1(4, mm.x, dd.x, cc.x, t0);
        P1(5, mm.y, dd.y, cc.y, t1);
        P1(6, mm.z, dd.z, cc.z, t2);
        P1(7, mm.w, dd.w, cc.w, t3);
    }
#undef P1
    {
#pragma unroll
        for (int j = 0; j < 12; j++) {
            float x = acc[j];
#pragma unroll
            for (int off = 32; off; off >>= 1) x += __shfl_xor(x, off);
            if (lane == 0) s_red[wid * 13 + j] = x;
        }
        float mx = statmax;
#pragma unroll
        for (int off = 32; off; off >>= 1) mx = fmaxf(mx, __shfl_xor(mx, off));
        if (lane == 0) s_red[wid * 13 + 12] = mx;
        __syncthreads();
        if (tid < 13) {
            float s = s_red[tid];
#pragma unroll
            for (int w = 1; w < NW; w++) {
                float x = s_red[w * 13 + tid];
                s = (tid == 12) ? fmaxf(s, x) : (s + x);
            }
            s_bc[tid] = s;
        }
        __syncthreads();
    }
    const float visible = fmaxf(s_bc[0], 1.f);
    const float sum_d = s_bc[1];
    const float inv_vis = 1.f / visible;
    const float mean0 = s_bc[2] * inv_vis, ex20 = s_bc[3] * inv_vis;
    const float mean1 = s_bc[4] * inv_vis, ex21 = s_bc[5] * inv_vis;
    const float Sz    = s_bc[6];
    const float mean2 = Sz * inv_vis,      ex22 = s_bc[7] * inv_vis;
    const float mean3 = s_bc[8] * inv_vis, ex23 = s_bc[9] * inv_vis;
    const float n1    = s_bc[10];
    const float Scz   = s_bc[11];
    const float gmax  = s_bc[12];
    const float meanc = n1 * inv_vis;

    const float var1_raw = ex21 - mean1 * mean1;
    const float var2_raw = ex22 - mean2 * mean2;
    const float istd0 = 1.f / sqrtf(fmaxf(ex20 - mean0 * mean0, 1e-6f));
    const float istd1 = 1.f / sqrtf(fmaxf(var1_raw, 1e-6f));
    const float istd2 = 1.f / sqrtf(fmaxf(var2_raw, 1e-6f));
    const float istd3 = 1.f / sqrtf(fmaxf(ex23 - mean3 * mean3, 1e-6f));
    const float istdc = 1.f / sqrtf(fmaxf(meanc - meanc * meanc, 1e-6f));

    const int L = (int)(visible + 0.5f);

    const float st0 = stats[row * 5 + 0], st1 = stats[row * 5 + 1];
    const float st2 = stats[row * 5 + 2], st4 = stats[row * 5 + 4];

    const float src_total = fmaxf(sum_d, 1.f);
    const float src_mean = src_total * inv_vis;
    const float ref_ms = fmaxf(st2, 1.f);
    const float rate_scale = fminf(fmaxf(ref_ms / fmaxf(src_mean, 1.f), 0.55f), 1.95f);
    const float speech_budget = src_total * rate_scale;
    const float pause_ratio = fminf(fmaxf(st0, 0.f), 0.49f);
    const float boundary_ratio = fminf(fmaxf(st4, 0.f), 1.f);
    const float mean_pause = fmaxf(st1, 0.f);
    const float pfr = speech_budget * pause_ratio / fmaxf(1.f - pause_ratio, 0.2f);
    const float pfe = visible * boundary_ratio * mean_pause;
    float pause_budget = fmaxf(0.35f * pfr + 0.65f * pfe, 0.f);
    pause_budget = fminf(pause_budget, speech_budget * 0.8f);

    float conf = 0.2f + 0.3f * fminf(fmaxf(st0, 0.f), 1.f)
               + 0.25f * fminf(fmaxf(st4, 0.f), 1.f)
               + 0.2f * mean2
               + 0.1f * expf(-fmaxf(var1_raw, 0.f)) + 0.05f;
    conf = fminf(fmaxf(conf, 0.05f), 1.f);

    const float ratio = fminf(fmaxf(fmaxf(0.3f, gmax), 0.f), 1.f);
    int kint = (int)rintf(visible * ratio);
    kint = max(1, min(kint, L));

    // ---- Closed-form cosine gate (cue is 0/1: sp takes two values hi/lo)
    const float hi = fminf(fmaxf((1.f - meanc) * istdc, -1.5f), 1.5f);
    const float lo = fminf(fmaxf((0.f - meanc) * istdc, -1.5f), 1.5f);
    float pcoef;
    {
        float n0 = visible - n1;
        float sum_sp2 = hi * hi * n1 + lo * lo * n0;
        float sum_rb2 = istd2 * istd2 * visible * fmaxf(var2_raw, 0.f);
        float c1 = Scz - mean2 * n1;
        float c0 = (Sz - mean2 * visible) - c1;
        float dotv = istd2 * (hi * c1 + lo * c0);
        float xn = sqrtf(fmaxf(sum_sp2, 1e-6f));
        float yn = sqrtf(fmaxf(sum_rb2, 1e-6f));
        float agree = fminf(fmaxf(dotv / fmaxf(xn * yn, 1e-6f), -1.f), 1.f);
        float gate = 1.f / (1.f + expf(-(agree - 0.15f) * 4.f));
        pcoef = 0.35f * (0.05f + 0.5f * gate);
    }

    // ---- Phase 3: speech scores -> LDS (raw), pause scores -> regs (only persistent array)
    float ps[EPT];
    float vtmp[EPT];
    {
        float4 ca = c4[tid * 2], cb = c4[tid * 2 + 1];
        float4 da = d4[tid * 2], db = d4[tid * 2 + 1];
        float cnext = (tid == NTH - 1) ? 1.f : s_c0[tid + 1];
#define P3(ii, C_, PF_, D_, TR_) {                                              \
        float4 tr_ = (TR_); float vv = 0.f, pp = 0.f;                           \
        if (base + (ii) < L) {                                                  \
            float z1 = (tr_.y - mean1) * istd1;                                 \
            float z3 = (tr_.w - mean3) * istd3;                                 \
            vv = expf(log1pf(fmaxf((D_), 0.f)) + 0.45f * z1 + 0.3f * z3         \
                      + 0.2f * (PF_));                                          \
            float z0 = (tr_.x - mean0) * istd0;                                 \
            float rbv = (tr_.z - mean2) * istd2;                                \
            pp = expf(1.1f * z0 + 1.5f * rbv + pcoef * (lo + (C_) * (hi - lo))); } \
        vtmp[ii] = vv; s_v[1 + base + (ii)] = vv; ps[ii] = pp; }
        {
            float4 t0 = t4[base + 0], t1 = t4[base + 1], t2 = t4[base + 2], t3 = t4[base + 3];
            P3(0, ca.x, ca.y, da.x, t0);
            P3(1, ca.y, ca.z, da.y, t1);
            P3(2, ca.z, ca.w, da.z, t2);
            P3(3, ca.w, cb.x, da.w, t3);
        }
        {
            float4 t0 = t4[base + 4], t1 = t4[base + 5], t2 = t4[base + 6], t3 = t4[base + 7];
            P3(4, cb.x, cb.y, db.x, t0);
            P3(5, cb.y, cb.z, db.y, t1);
            P3(6, cb.z, cb.w, db.z, t2);
            P3(7, cb.w, cnext, db.w, t3);
        }
#undef P3
    }
    if (tid == 0) { s_v[0] = 0.f; s_v[NTH * EPT + 1] = 0.f; }
    // clear radix hist buffer 0 under the same barrier
    for (int j = tid; j < NW * 256; j += NTH) s_hist[j] = 0u;
    __syncthreads();

    // ---- Phase 3b: smooth3 sum (own raw in regs, edges from LDS); vtmp dies after
    float acc1[1] = {0.f};
    {
        float prev = s_v[base];
        float nxt_edge = s_v[1 + base + EPT];
#pragma unroll
        for (int i = 0; i < EPT; i++) {
            float cur = vtmp[i];
            float nxt = (i < 7) ? vtmp[i + 1] : nxt_edge;
            float smv = (base + i < L) ? (prev + cur + nxt) * (1.f / 3.f) : 0.f;
            acc1[0] += smv; prev = cur;
        }
    }
    block_reduce<1>(acc1, s_red, s_bc);
    const float spe_scale = speech_budget / fmaxf(s_bc[0], 1e-6f);

    // ---- Phase 4: exact radix select, ping-pong histograms (2 barriers/round)
    unsigned pref = 0u, cmaskk = 0u;
    unsigned kk = (unsigned)kint;
    unsigned cnt_eq = 0u;
    int cur = 0;
#pragma unroll 1
    for (int r = 0; r < 4; r++) {
        const int shift = 24 - 8 * r;
#pragma unroll
        for (int i = 0; i < EPT; i++) {
            unsigned b = __float_as_uint(ps[i]);
            if ((b & cmaskk) == pref)
                atomicAdd(&s_hist[cur * (NW * 256) + wid * 256 + ((b >> shift) & 0xFFu)], 1u);
        }
        __syncthreads();
        if (wid == 0) {
            unsigned bb = lane * 4;
            unsigned h0 = 0, h1 = 0, h2 = 0, h3 = 0;
#pragma unroll
            for (int w = 0; w < NW; w++) {
                h0 += s_hist[cur * (NW * 256) + w * 256 + bb + 0];
                h1 += s_hist[cur * (NW * 256) + w * 256 + bb + 1];
                h2 += s_hist[cur * (NW * 256) + w * 256 + bb + 2];
                h3 += s_hist[cur * (NW * 256) + w * 256 + bb + 3];
            }
            unsigned s = h0 + h1 + h2 + h3;
            unsigned vs = s;
#pragma unroll
            for (int off = 1; off < 64; off <<= 1) {
                unsigned u = __shfl_down(vs, off);
                if (lane + off < 64) vs += u;
            }
            unsigned vnext = __shfl_down(vs, 1);
            if (lane == 63) vnext = 0u;
            unsigned higher = vs - s;
            unsigned S3 = higher + h3;
            unsigned S2 = S3 + h2;
            unsigned S1 = S2 + h1;
            unsigned S0 = S1 + h0;
            if (S3 >= kk && vnext < kk)    { s_sel[0] = bb + 3; s_sel[1] = vnext; s_sel[2] = S3; }
            else if (S2 >= kk && S3 < kk)  { s_sel[0] = bb + 2; s_sel[1] = S3;    s_sel[2] = S2; }
            else if (S1 >= kk && S2 < kk)  { s_sel[0] = bb + 1; s_sel[1] = S2;    s_sel[2] = S1; }
            else if (S0 >= kk && S1 < kk)  { s_sel[0] = bb + 0; s_sel[1] = S1;    s_sel[2] = S0; }
        } else if (r < 3) {
            for (int j = tid - 64; j < NW * 256; j += NTH - 64)
                s_hist[(cur ^ 1) * (NW * 256) + j] = 0u;
        }
        __syncthreads();
        pref |= s_sel[0] << shift;
        cmaskk |= 0xFFu << shift;
        kk -= s_sel[1];
        if (r == 3) cnt_eq = s_sel[2] - s_sel[1];
        cur ^= 1;
    }
    const unsigned thr_bits = pref;
    const unsigned keep_eq = kk;

    // ---- Phase 5: keep top-k; stable ascending-index tie-break only if ties span the cut
    float accp[1] = {0.f};
    if (cnt_eq == keep_eq) {
#pragma unroll
        for (int c = 0; c < EPT; c++) {
            unsigned b = __float_as_uint(ps[c]);
            float pv = (b >= thr_bits) ? ps[c] : 0.f;
            ps[c] = pv; accp[0] += pv;
        }
    } else {
        unsigned teq = 0;
#pragma unroll
        for (int i = 0; i < EPT; i++) teq += (__float_as_uint(ps[i]) == thr_bits) ? 1u : 0u;
        unsigned winc = teq;
#pragma unroll
        for (int off = 1; off < 64; off <<= 1) {
            unsigned u = __shfl_up(winc, off);
            if (lane >= off) winc += u;
        }
        if (lane == 63) s_wu[wid] = winc;
        __syncthreads();
        unsigned rank = winc - teq;
#pragma unroll
        for (int w = 0; w < NW; w++) if (w < wid) rank += s_wu[w];
#pragma unroll
        for (int c = 0; c < EPT; c++) {
            unsigned b = __float_as_uint(ps[c]);
            bool eq = (b == thr_bits);
            bool keep = (b > thr_bits) || (eq && rank < keep_eq);
            if (eq) rank++;
            float pv = keep ? ps[c] : 0.f;
            ps[c] = pv; accp[0] += pv;
        }
    }
    block_reduce<1>(accp, s_red, s_bc);
    const float pa_scale = pause_budget / fmaxf(s_bc[0], 1e-6f);

    // ---- Phase 6: recompute smooth3 from LDS, reload dur, write everything + scan
    const float inv_alloc = 1.f / fmaxf(speech_budget + pause_budget, 1e-6f);
    float spv[EPT], pav[EPT], scn[EPT];
    float run = 0.f;
    {
        float4 da = d4[tid * 2], db = d4[tid * 2 + 1];
        float dr[EPT];
        dr[0] = da.x; dr[1] = da.y; dr[2] = da.z; dr[3] = da.w;
        dr[4] = db.x; dr[5] = db.y; dr[6] = db.z; dr[7] = db.w;
        float prev = s_v[base];
#pragma unroll
        for (int i = 0; i < EPT; i++) {
            float curv = s_v[1 + base + i];
            float nxt = s_v[2 + base + i];
            bool in = base + i < L;
            float smv = in ? (prev + curv + nxt) * (1.f / 3.f) : 0.f;
            prev = curv;
            float spe = smv * spe_scale;
            float pae = ps[i] * pa_scale;
            spv[i] = spe; pav[i] = pae;
            run += in ? (spe + pae - dr[i]) : 0.f;
            scn[i] = run;
        }
    }
    {
        nfloat4 a = {spv[0], spv[1], spv[2], spv[3]};
        nfloat4 b = {spv[4], spv[5], spv[6], spv[7]};
        __builtin_nontemporal_store(a, &spe4[tid * 2]);
        __builtin_nontemporal_store(b, &spe4[tid * 2 + 1]);
        nfloat4 c = {pav[0], pav[1], pav[2], pav[3]};
        nfloat4 d = {pav[4], pav[5], pav[6], pav[7]};
        __builtin_nontemporal_store(c, &pae4[tid * 2]);
        __builtin_nontemporal_store(d, &pae4[tid * 2 + 1]);
        nfloat4 e = {(spv[0] + pav[0]) * inv_alloc, (spv[1] + pav[1]) * inv_alloc,
                     (spv[2] + pav[2]) * inv_alloc, (spv[3] + pav[3]) * inv_alloc};
        nfloat4 f = {(spv[4] + pav[4]) * inv_alloc, (spv[5] + pav[5]) * inv_alloc,
                     (spv[6] + pav[6]) * inv_alloc, (spv[7] + pav[7]) * inv_alloc};
        __builtin_nontemporal_store(e, &al4[tid * 2]);
        __builtin_nontemporal_store(f, &al4[tid * 2 + 1]);
    }
    {
        float total = run;
        float winc = total;
#pragma unroll
        for (int off = 1; off < 64; off <<= 1) {
            float u = __shfl_up(winc, off);
            if (lane >= off) winc += u;
        }
        if (lane == 63) s_ws[wid] = winc;
        __syncthreads();
        float off0 = winc - total;
#pragma unroll
        for (int w = 0; w < NW; w++) if (w < wid) off0 += s_ws[w];
        float pcv[EPT], bkv[EPT];
#pragma unroll
        for (int i = 0; i < EPT; i++) {
            bool in = base + i < L;
            float incl = off0 + scn[i];
            pcv[i] = in ? incl : 0.f;
            bkv[i] = in ? fmaxf(incl, 0.f) : 0.f;
        }
        nfloat4 a = {pcv[0], pcv[1], pcv[2], pcv[3]};
        nfloat4 b = {pcv[4], pcv[5], pcv[6], pcv[7]};
        __builtin_nontemporal_store(a, &pc4[tid * 2]);
        __builtin_nontemporal_store(b, &pc4[tid * 2 + 1]);
        nfloat4 c = {bkv[0], bkv[1], bkv[2], bkv[3]};
        nfloat4 d = {bkv[4], bkv[5], bkv[6], bkv[7]};
        __builtin_nontemporal_store(c, &bk4[tid * 2]);
        __builtin_nontemporal_store(d, &bk4[tid * 2 + 1]);
    }

    if (tid == 0) {
        o_sb[row] = speech_budget;
        o_pb[row] = pause_budget;
        o_cf[row] = conf;
    }
}

extern "C" void kernel_launch(void* const* d_in, const int* in_sizes, int n_in,
                              void* d_out, int out_size, void* d_ws, size_t ws_size,
                              hipStream_t stream) {
    const float* dur   = (const float*)d_in[0];
    const float* stats = (const float*)d_in[1];
    const float* trace = (const float*)d_in[2];
    const float* mask  = (const float*)d_in[3];
    const float* cue   = (const float*)d_in[4];
    float* out = (float*)d_out;

    teacher_kernel<<<dim3(BATCH), dim3(NTH), 0, stream>>>(dur, stats, trace, mask, cue, out);
}

// Round 10
// 98.931 us; speedup vs baseline: 1.6555x; 1.6555x over previous
//
#include <hip/hip_runtime.h>

#define T 8192
#define BATCH 512
#define NTH 1024
#define EPT 8
#define NW 16

// padded histogram addressing: bin b -> b + (b>>5)  (32 bins share +1 pad word)
#define HPAD(b) ((b) + ((b) >> 5))
#define H0C 2112           // 2048 bins padded
#define H1TOT 2112
#define H2TOT 1056         // 1024 bins padded

template <int N>
__device__ __forceinline__ void block_reduce(float (&v)[N], float* s_red, float* s_bc) {
    int lane = threadIdx.x & 63, wid = threadIdx.x >> 6;
#pragma unroll
    for (int j = 0; j < N; j++) {
        float x = v[j];
#pragma unroll
        for (int off = 32; off; off >>= 1) x += __shfl_xor(x, off);
        if (lane == 0) s_red[wid * N + j] = x;
    }
    __syncthreads();
    if (threadIdx.x < N) {
        float s = 0.f;
#pragma unroll
        for (int w = 0; w < NW; w++) s += s_red[w * N + threadIdx.x];
        s_bc[threadIdx.x] = s;
    }
    __syncthreads();
}

__global__ __launch_bounds__(NTH) void teacher_kernel(
    const float* __restrict__ dur, const float* __restrict__ stats,
    const float* __restrict__ trace, const float* __restrict__ mask,
    const float* __restrict__ cue, float* __restrict__ out)
{
    const int row = blockIdx.x;
    const int tid = threadIdx.x;
    const int lane = tid & 63, wid = tid >> 6;

    __shared__ unsigned s_h0[4 * H0C];          // 33 KB round-0 hist, 4 copies
    __shared__ unsigned s_h1[H1TOT];            // 8.25 KB
    __shared__ unsigned s_h2[H2TOT];            // 4.1 KB
    __shared__ float s_red[NW * 13];
    __shared__ float s_bc[16];
    __shared__ float s_vL[NW][EPT], s_vR[NW][EPT];
    __shared__ float s_part[EPT * NW];
    __shared__ float s_offs[EPT * NW];
    __shared__ unsigned s_sel[4];
    __shared__ unsigned s_wu[NW];

    const size_t BT = (size_t)BATCH * T;
    const size_t rbase = (size_t)row * T;
    const float* drow = dur + rbase;
    const float* mrow = mask + rbase;
    const float* crow = cue + rbase;
    const float4* trow = (const float4*)(trace + rbase * 4);

    float* o_spe = out + rbase;
    float* o_pae = out + BT + rbase;
    float* o_sb  = out + 2 * BT;
    float* o_pb  = out + 2 * BT + BATCH;
    float* o_al  = out + 2 * BT + 2 * BATCH + rbase;
    float* o_cf  = out + 3 * BT + 2 * BATCH;
    float4* o_tc = ((float4*)(out + 3 * BT + 3 * BATCH)) + rbase;
    float* o_pc  = out + 7 * BT + 3 * BATCH + rbase;
    float* o_bk  = out + 8 * BT + 3 * BATCH + rbase;

    float durr[EPT];

    // ---- Phase 1: full input read, trace_ctx write, 12 masked sums + stats max.
    // Also clear the round-0 histogram before the first barrier (free).
    float statmax = (tid < BATCH) ? fminf(fmaxf(stats[tid * 5 + 4], 0.f), 1.f) : 0.f;
    float acc[12];
#pragma unroll
    for (int j = 0; j < 12; j++) acc[j] = 0.f;
#pragma unroll
    for (int i = 0; i < EPT; i++) {
        int t = i * NTH + tid;
        float m = mrow[t];
        float d = drow[t];
        float c = crow[t];
        float4 tr = trow[t];
        durr[i] = d;
        o_tc[t] = make_float4(tr.x * m, tr.y * m, tr.z * m, tr.w * m);
        acc[0] += m;            acc[1] += d * m;
        acc[2] += tr.x * m;     acc[3] += tr.x * tr.x * m;
        acc[4] += tr.y * m;     acc[5] += tr.y * tr.y * m;
        acc[6] += tr.z * m;     acc[7] += tr.z * tr.z * m;
        acc[8] += tr.w * m;     acc[9] += tr.w * tr.w * m;
        acc[10] += c * m;       acc[11] += c * tr.z * m;
    }
    for (int j = tid; j < 4 * H0C; j += NTH) s_h0[j] = 0u;
    {
#pragma unroll
        for (int j = 0; j < 12; j++) {
            float x = acc[j];
#pragma unroll
            for (int off = 32; off; off >>= 1) x += __shfl_xor(x, off);
            if (lane == 0) s_red[wid * 13 + j] = x;
        }
        float mx = statmax;
#pragma unroll
        for (int off = 32; off; off >>= 1) mx = fmaxf(mx, __shfl_xor(mx, off));
        if (lane == 0) s_red[wid * 13 + 12] = mx;
        __syncthreads();
        if (tid < 13) {
            float s = s_red[tid];
#pragma unroll
            for (int w = 1; w < NW; w++) {
                float x = s_red[w * 13 + tid];
                s = (tid == 12) ? fmaxf(s, x) : (s + x);
            }
            s_bc[tid] = s;
        }
        __syncthreads();
    }
    const float visible = fmaxf(s_bc[0], 1.f);
    const float sum_d = s_bc[1];
    const float inv_vis = 1.f / visible;
    const float mean0 = s_bc[2] * inv_vis, ex20 = s_bc[3] * inv_vis;
    const float mean1 = s_bc[4] * inv_vis, ex21 = s_bc[5] * inv_vis;
    const float Sz    = s_bc[6];
    const float mean2 = Sz * inv_vis,      ex22 = s_bc[7] * inv_vis;
    const float mean3 = s_bc[8] * inv_vis, ex23 = s_bc[9] * inv_vis;
    const float n1    = s_bc[10];
    const float Scz   = s_bc[11];
    const float gmax  = s_bc[12];
    const float meanc = n1 * inv_vis;

    const float var1_raw = ex21 - mean1 * mean1;
    const float var2_raw = ex22 - mean2 * mean2;
    const float istd0 = 1.f / sqrtf(fmaxf(ex20 - mean0 * mean0, 1e-6f));
    const float istd1 = 1.f / sqrtf(fmaxf(var1_raw, 1e-6f));
    const float istd2 = 1.f / sqrtf(fmaxf(var2_raw, 1e-6f));
    const float istd3 = 1.f / sqrtf(fmaxf(ex23 - mean3 * mean3, 1e-6f));
    const float istdc = 1.f / sqrtf(fmaxf(meanc - meanc * meanc, 1e-6f));

    const int L = (int)(visible + 0.5f);

    const float st0 = stats[row * 5 + 0], st1 = stats[row * 5 + 1];
    const float st2 = stats[row * 5 + 2], st4 = stats[row * 5 + 4];

    const float src_total = fmaxf(sum_d, 1.f);
    const float src_mean = src_total * inv_vis;
    const float ref_ms = fmaxf(st2, 1.f);
    const float rate_scale = fminf(fmaxf(ref_ms / fmaxf(src_mean, 1.f), 0.55f), 1.95f);
    const float speech_budget = src_total * rate_scale;
    const float pause_ratio = fminf(fmaxf(st0, 0.f), 0.49f);
    const float boundary_ratio = fminf(fmaxf(st4, 0.f), 1.f);
    const float mean_pause = fmaxf(st1, 0.f);
    const float pfr = speech_budget * pause_ratio / fmaxf(1.f - pause_ratio, 0.2f);
    const float pfe = visible * boundary_ratio * mean_pause;
    float pause_budget = fmaxf(0.35f * pfr + 0.65f * pfe, 0.f);
    pause_budget = fminf(pause_budget, speech_budget * 0.8f);

    float conf = 0.2f + 0.3f * fminf(fmaxf(st0, 0.f), 1.f)
               + 0.25f * fminf(fmaxf(st4, 0.f), 1.f)
               + 0.2f * mean2
               + 0.1f * expf(-fmaxf(var1_raw, 0.f)) + 0.05f;
    conf = fminf(fmaxf(conf, 0.05f), 1.f);

    const float ratio = fminf(fmaxf(fmaxf(0.3f, gmax), 0.f), 1.f);
    int kint = (int)rintf(visible * ratio);
    kint = max(1, min(kint, L));

    // ---- Closed-form cosine gate (cue is 0/1)
    const float hi = fminf(fmaxf((1.f - meanc) * istdc, -1.5f), 1.5f);
    const float lo = fminf(fmaxf((0.f - meanc) * istdc, -1.5f), 1.5f);
    float pcoef;
    {
        float n0 = visible - n1;
        float sum_sp2 = hi * hi * n1 + lo * lo * n0;
        float sum_rb2 = istd2 * istd2 * visible * fmaxf(var2_raw, 0.f);
        float c1 = Scz - mean2 * n1;
        float c0 = (Sz - mean2 * visible) - c1;
        float dotv = istd2 * (hi * c1 + lo * c0);
        float xn = sqrtf(fmaxf(sum_sp2, 1e-6f));
        float yn = sqrtf(fmaxf(sum_rb2, 1e-6f));
        float agree = fminf(fmaxf(dotv / fmaxf(xn * yn, 1e-6f), -1.f), 1.f);
        float gate = 1.f / (1.f + expf(-(agree - 0.15f) * 4.f));
        pcoef = 0.35f * (0.05f + 0.5f * gate);
    }

    // ---- Phase 3: raw speech scores v + pause scores ps (L3-hot reloads)
    float v[EPT], ps[EPT];
#pragma unroll
    for (int i = 0; i < EPT; i++) {
        int t = i * NTH + tid;
        float c = crow[t];
        float pf = (t == T - 1) ? 1.f : crow[t + 1];
        float4 tr = trow[t];
        float vv = 0.f, pp = 0.f;
        if (t < L) {
            float z1 = (tr.y - mean1) * istd1;
            float z3 = (tr.w - mean3) * istd3;
            vv = expf(log1pf(fmaxf(durr[i], 0.f)) + 0.45f * z1 + 0.3f * z3 + 0.2f * pf);
            float z0 = (tr.x - mean0) * istd0;
            float rbv = (tr.z - mean2) * istd2;
            float spv = lo + c * (hi - lo);
            pp = expf(1.1f * z0 + 1.5f * rbv + pcoef * spv);
        }
        v[i] = vv; ps[i] = pp;
        if (lane == 0)  s_vL[wid][i] = vv;
        if (lane == 63) s_vR[wid][i] = vv;
    }
    __syncthreads();   // h0 cleared (phase 1), edges visible

    // ---- Radix select: 3 rounds (11 / 11 / 10 bits), padded bank-clean hists
    unsigned kk = (unsigned)kint;
    unsigned b0sel, b1sel, b2sel, cnt_eq, keep_eq;

    // Round 0: bits [31:21], 2048 bins, 4 privatized copies
    {
        const unsigned coff = (unsigned)(wid >> 2) * H0C;
#pragma unroll
        for (int i = 0; i < EPT; i++) {
            unsigned b = __float_as_uint(ps[i]) >> 21;
            atomicAdd(&s_h0[coff + HPAD(b)], 1u);
        }
        __syncthreads();
        if (wid == 0) {
            unsigned local = 0;
#pragma unroll 1
            for (int j = 0; j < 32; j++) {
                unsigned a = (unsigned)lane * 33u + (unsigned)j;
                local += s_h0[a] + s_h0[H0C + a] + s_h0[2 * H0C + a] + s_h0[3 * H0C + a];
            }
            unsigned vs = local;
#pragma unroll
            for (int off = 1; off < 64; off <<= 1) {
                unsigned u = __shfl_down(vs, off);
                if (lane + off < 64) vs += u;
            }
            unsigned S = vs - local;
#pragma unroll 1
            for (int j = 31; j >= 0; j--) {
                unsigned a = (unsigned)lane * 33u + (unsigned)j;
                unsigned hj = s_h0[a] + s_h0[H0C + a] + s_h0[2 * H0C + a] + s_h0[3 * H0C + a];
                unsigned Sn = S + hj;
                if (Sn >= kk && S < kk) { s_sel[0] = lane * 32 + j; s_sel[1] = S; }
                S = Sn;
            }
        } else {
            for (int j = tid - 64; j < H1TOT; j += NTH - 64) s_h1[j] = 0u;
        }
        __syncthreads();
        b0sel = s_sel[0];
        kk -= s_sel[1];
    }

    // Round 1: bits [20:10], 2048 bins, participants ~n/2048
    {
#pragma unroll
        for (int i = 0; i < EPT; i++) {
            unsigned b = __float_as_uint(ps[i]);
            if ((b >> 21) == b0sel)
                atomicAdd(&s_h1[HPAD((b >> 10) & 0x7FFu)], 1u);
        }
        __syncthreads();
        if (wid == 0) {
            unsigned local = 0;
#pragma unroll 1
            for (int j = 0; j < 32; j++) local += s_h1[(unsigned)lane * 33u + (unsigned)j];
            unsigned vs = local;
#pragma unroll
            for (int off = 1; off < 64; off <<= 1) {
                unsigned u = __shfl_down(vs, off);
                if (lane + off < 64) vs += u;
            }
            unsigned S = vs - local;
#pragma unroll 1
            for (int j = 31; j >= 0; j--) {
                unsigned hj = s_h1[(unsigned)lane * 33u + (unsigned)j];
                unsigned Sn = S + hj;
                if (Sn >= kk && S < kk) { s_sel[0] = lane * 32 + j; s_sel[1] = S; }
                S = Sn;
            }
        } else {
            for (int j = tid - 64; j < H2TOT; j += NTH - 64) s_h2[j] = 0u;
        }
        __syncthreads();
        b1sel = s_sel[0];
        kk -= s_sel[1];
    }

    // Round 2: bits [9:0], 1024 bins
    {
        const unsigned pref22 = (b0sel << 11) | b1sel;
#pragma unroll
        for (int i = 0; i < EPT; i++) {
            unsigned b = __float_as_uint(ps[i]);
            if ((b >> 10) == pref22)
                atomicAdd(&s_h2[HPAD(b & 0x3FFu)], 1u);
        }
        __syncthreads();
        if (wid == 0) {
            unsigned local = 0;
#pragma unroll 1
            for (int j = 0; j < 16; j++) {
                unsigned bb = (unsigned)lane * 16u + (unsigned)j;
                local += s_h2[HPAD(bb)];
            }
            unsigned vs = local;
#pragma unroll
            for (int off = 1; off < 64; off <<= 1) {
                unsigned u = __shfl_down(vs, off);
                if (lane + off < 64) vs += u;
            }
            unsigned S = vs - local;
#pragma unroll 1
            for (int j = 15; j >= 0; j--) {
                unsigned bb = (unsigned)lane * 16u + (unsigned)j;
                unsigned hj = s_h2[HPAD(bb)];
                unsigned Sn = S + hj;
                if (Sn >= kk && S < kk) { s_sel[0] = bb; s_sel[1] = S; s_sel[2] = Sn; }
                S = Sn;
            }
        }
        __syncthreads();
        b2sel = s_sel[0];
        keep_eq = kk - s_sel[1];
        cnt_eq = s_sel[2] - s_sel[1];
    }
    const unsigned thr_bits = (b0sel << 21) | (b1sel << 10) | b2sel;

    // ---- Phase 5: keep top-k (tie-break in ascending t only if ties straddle the cut)
    float accm[2] = {0.f, 0.f};    // [0]=kept pause sum, [1]=smooth sum
    if (cnt_eq == keep_eq) {
#pragma unroll
        for (int c = 0; c < EPT; c++) {
            unsigned b = __float_as_uint(ps[c]);
            float pv = (b >= thr_bits) ? ps[c] : 0.f;
            ps[c] = pv; accm[0] += pv;
        }
    } else {
        unsigned carry_eq = 0u;
#pragma unroll
        for (int c = 0; c < EPT; c++) {
            unsigned b = __float_as_uint(ps[c]);
            bool eq = (b == thr_bits);
            unsigned long long bal = __ballot(eq);
            unsigned lpre = (unsigned)__popcll(bal & ((1ull << lane) - 1ull));
            unsigned wc = (unsigned)__popcll(bal);
            if (lane == 0) s_wu[wid] = wc;
            __syncthreads();
            unsigned woff = 0u, tot = 0u;
#pragma unroll
            for (int w = 0; w < NW; w++) { unsigned x = s_wu[w]; if (w < wid) woff += x; tot += x; }
            __syncthreads();
            unsigned rank = carry_eq + woff + lpre;
            bool keep = (b > thr_bits) || (eq && rank < keep_eq);
            float pv = keep ? ps[c] : 0.f;
            ps[c] = pv; accm[0] += pv;
            carry_eq += tot;
        }
    }

    // ---- smooth3 on raw v (shuffles + wave-edge LDS), merged into same reduce
#pragma unroll
    for (int i = 0; i < EPT; i++) {
        int t = i * NTH + tid;
        float vl = __shfl_up(v[i], 1);
        if (lane == 0)
            vl = (wid > 0) ? s_vR[wid - 1][i] : ((i > 0) ? s_vR[NW - 1][i - 1] : 0.f);
        float vr = __shfl_down(v[i], 1);
        if (lane == 63)
            vr = (wid < NW - 1) ? s_vL[wid + 1][i] : ((i + 1 < EPT) ? s_vL[0][i + 1] : 0.f);
        float smv = 0.f;
        if (t < L) smv = (vl + v[i] + vr) * (1.f / 3.f);
        v[i] = smv; accm[1] += smv;
    }
    block_reduce<2>(accm, s_red, s_bc);
    const float pa_scale = pause_budget / fmaxf(s_bc[0], 1e-6f);
    const float spe_scale = speech_budget / fmaxf(s_bc[1], 1e-6f);

    // ---- Phase 6: writes + 2-barrier block scan
    const float inv_alloc = 1.f / fmaxf(speech_budget + pause_budget, 1e-6f);
#pragma unroll
    for (int c = 0; c < EPT; c++) {
        int t = c * NTH + tid;
        bool in = t < L;
        float spe = v[c] * spe_scale;
        float pae = ps[c] * pa_scale;
        o_spe[t] = spe;
        o_pae[t] = pae;
        o_al[t] = (spe + pae) * inv_alloc;
        float x = in ? (spe + pae - durr[c]) : 0.f;
#pragma unroll
        for (int off = 1; off < 64; off <<= 1) {
            float u = __shfl_up(x, off);
            if (lane >= off) x += u;
        }
        v[c] = x;                        // per-lane inclusive scan within wave
        if (lane == 63) s_part[c * NW + wid] = x;
    }
    __syncthreads();
    if (wid == 0) {   // scan 128 wave-partials: 2 per lane
        float a = s_part[2 * lane], b = s_part[2 * lane + 1];
        float pair = a + b;
        float inc = pair;
#pragma unroll
        for (int off = 1; off < 64; off <<= 1) {
            float u = __shfl_up(inc, off);
            if (lane >= off) inc += u;
        }
        float excl = inc - pair;
        s_offs[2 * lane] = excl;
        s_offs[2 * lane + 1] = excl + a;
    }
    __syncthreads();
#pragma unroll
    for (int c = 0; c < EPT; c++) {
        int t = c * NTH + tid;
        bool in = t < L;
        float incl = s_offs[c * NW + wid] + v[c];
        o_pc[t] = in ? incl : 0.f;
        o_bk[t] = in ? fmaxf(incl, 0.f) : 0.f;
    }

    if (tid == 0) {
        o_sb[row] = speech_budget;
        o_pb[row] = pause_budget;
        o_cf[row] = conf;
    }
}

extern "C" void kernel_launch(void* const* d_in, const int* in_sizes, int n_in,
                              void* d_out, int out_size, void* d_ws, size_t ws_size,
                              hipStream_t stream) {
    const float* dur   = (const float*)d_in[0];
    const float* stats = (const float*)d_in[1];
    const float* trace = (const float*)d_in[2];
    const float* mask  = (const float*)d_in[3];
    const float* cue   = (const float*)d_in[4];
    float* out = (float*)d_out;

    teacher_kernel<<<dim3(BATCH), dim3(NTH), 0, stream>>>(dur, stats, trace, mask, cue, out);
}

// Round 11
// 85.335 us; speedup vs baseline: 1.9192x; 1.1593x over previous
//
#include <hip/hip_runtime.h>

#define T 8192
#define BATCH 512
#define NTH 1024
#define EPT 8
#define NW 16

__global__ __launch_bounds__(NTH) void teacher_kernel(
    const float* __restrict__ dur, const float* __restrict__ stats,
    const float* __restrict__ trace, const float* __restrict__ mask,
    const float* __restrict__ cue, float* __restrict__ out)
{
    const int row = blockIdx.x;
    const int tid = threadIdx.x;
    const int lane = tid & 63, wid = tid >> 6;

    __shared__ unsigned s_hist[2 * NW * 256];   // 32 KB ping-pong, per-wave copies
    __shared__ float s_red[NW * 13];
    __shared__ float s_vL[NW][EPT], s_vR[NW][EPT];
    __shared__ float s_part[EPT * NW];
    __shared__ unsigned s_wu[NW];

    const size_t BT = (size_t)BATCH * T;
    const size_t rbase = (size_t)row * T;
    const float* drow = dur + rbase;
    const float* mrow = mask + rbase;
    const float* crow = cue + rbase;
    const float4* trow = (const float4*)(trace + rbase * 4);

    float* o_spe = out + rbase;
    float* o_pae = out + BT + rbase;
    float* o_sb  = out + 2 * BT;
    float* o_pb  = out + 2 * BT + BATCH;
    float* o_al  = out + 2 * BT + 2 * BATCH + rbase;
    float* o_cf  = out + 3 * BT + 2 * BATCH;
    float4* o_tc = ((float4*)(out + 3 * BT + 3 * BATCH)) + rbase;
    float* o_pc  = out + 7 * BT + 3 * BATCH + rbase;
    float* o_bk  = out + 8 * BT + 3 * BATCH + rbase;

    float durr[EPT];

    // ---- Phase 1: full input read, 12 masked sums + stats max; clear own hist buf0 copy
    float statmax = (tid < BATCH) ? fminf(fmaxf(stats[tid * 5 + 4], 0.f), 1.f) : 0.f;
    float acc[12];
#pragma unroll
    for (int j = 0; j < 12; j++) acc[j] = 0.f;
#pragma unroll
    for (int i = 0; i < EPT; i++) {
        int t = i * NTH + tid;
        float m = mrow[t];
        float d = drow[t];
        float c = crow[t];
        float4 tr = trow[t];
        durr[i] = d;
        acc[0] += m;            acc[1] += d * m;
        acc[2] += tr.x * m;     acc[3] += tr.x * tr.x * m;
        acc[4] += tr.y * m;     acc[5] += tr.y * tr.y * m;
        acc[6] += tr.z * m;     acc[7] += tr.z * tr.z * m;
        acc[8] += tr.w * m;     acc[9] += tr.w * tr.w * m;
        acc[10] += c * m;       acc[11] += c * tr.z * m;
    }
    {   // clear this wave's buf0 histogram copy (wave-local, no barrier needed)
        int hb = wid * 256 + lane * 4;
        s_hist[hb] = 0u; s_hist[hb + 1] = 0u; s_hist[hb + 2] = 0u; s_hist[hb + 3] = 0u;
    }
    // wave partials -> LDS, ONE barrier, every wave redundantly folds 16 partials
#pragma unroll
    for (int j = 0; j < 12; j++) {
        float x = acc[j];
#pragma unroll
        for (int off = 32; off; off >>= 1) x += __shfl_xor(x, off);
        if (lane == 0) s_red[wid * 13 + j] = x;
    }
    {
        float mx = statmax;
#pragma unroll
        for (int off = 32; off; off >>= 1) mx = fmaxf(mx, __shfl_xor(mx, off));
        if (lane == 0) s_red[wid * 13 + 12] = mx;
    }
    __syncthreads();                                   // B1
    float colv = 0.f;
    if (lane == 12) {
        colv = s_red[12];
#pragma unroll
        for (int w = 1; w < NW; w++) colv = fmaxf(colv, s_red[w * 13 + 12]);
    } else if (lane < 12) {
#pragma unroll
        for (int w = 0; w < NW; w++) colv += s_red[w * 13 + lane];
    }
    const float visible = fmaxf(__shfl(colv, 0), 1.f);
    const float sum_d   = __shfl(colv, 1);
    const float inv_vis = 1.f / visible;
    const float mean0 = __shfl(colv, 2) * inv_vis, ex20 = __shfl(colv, 3) * inv_vis;
    const float mean1 = __shfl(colv, 4) * inv_vis, ex21 = __shfl(colv, 5) * inv_vis;
    const float Sz    = __shfl(colv, 6);
    const float mean2 = Sz * inv_vis,              ex22 = __shfl(colv, 7) * inv_vis;
    const float mean3 = __shfl(colv, 8) * inv_vis, ex23 = __shfl(colv, 9) * inv_vis;
    const float n1    = __shfl(colv, 10);
    const float Scz   = __shfl(colv, 11);
    const float gmax  = __shfl(colv, 12);
    const float meanc = n1 * inv_vis;

    const float var1_raw = ex21 - mean1 * mean1;
    const float var2_raw = ex22 - mean2 * mean2;
    const float istd0 = 1.f / sqrtf(fmaxf(ex20 - mean0 * mean0, 1e-6f));
    const float istd1 = 1.f / sqrtf(fmaxf(var1_raw, 1e-6f));
    const float istd2 = 1.f / sqrtf(fmaxf(var2_raw, 1e-6f));
    const float istd3 = 1.f / sqrtf(fmaxf(ex23 - mean3 * mean3, 1e-6f));
    const float istdc = 1.f / sqrtf(fmaxf(meanc - meanc * meanc, 1e-6f));

    const int L = (int)(visible + 0.5f);

    const float st0 = stats[row * 5 + 0], st1 = stats[row * 5 + 1];
    const float st2 = stats[row * 5 + 2], st4 = stats[row * 5 + 4];

    const float src_total = fmaxf(sum_d, 1.f);
    const float src_mean = src_total * inv_vis;
    const float ref_ms = fmaxf(st2, 1.f);
    const float rate_scale = fminf(fmaxf(ref_ms / fmaxf(src_mean, 1.f), 0.55f), 1.95f);
    const float speech_budget = src_total * rate_scale;
    const float pause_ratio = fminf(fmaxf(st0, 0.f), 0.49f);
    const float boundary_ratio = fminf(fmaxf(st4, 0.f), 1.f);
    const float mean_pause = fmaxf(st1, 0.f);
    const float pfr = speech_budget * pause_ratio / fmaxf(1.f - pause_ratio, 0.2f);
    const float pfe = visible * boundary_ratio * mean_pause;
    float pause_budget = fmaxf(0.35f * pfr + 0.65f * pfe, 0.f);
    pause_budget = fminf(pause_budget, speech_budget * 0.8f);

    float conf = 0.2f + 0.3f * fminf(fmaxf(st0, 0.f), 1.f)
               + 0.25f * fminf(fmaxf(st4, 0.f), 1.f)
               + 0.2f * mean2
               + 0.1f * expf(-fmaxf(var1_raw, 0.f)) + 0.05f;
    conf = fminf(fmaxf(conf, 0.05f), 1.f);

    const float ratio = fminf(fmaxf(fmaxf(0.3f, gmax), 0.f), 1.f);
    int kint = (int)rintf(visible * ratio);
    kint = max(1, min(kint, L));

    // ---- Closed-form cosine gate (cue is 0/1)
    const float hi = fminf(fmaxf((1.f - meanc) * istdc, -1.5f), 1.5f);
    const float lo = fminf(fmaxf((0.f - meanc) * istdc, -1.5f), 1.5f);
    float pcoef;
    {
        float n0 = visible - n1;
        float sum_sp2 = hi * hi * n1 + lo * lo * n0;
        float sum_rb2 = istd2 * istd2 * visible * fmaxf(var2_raw, 0.f);
        float c1 = Scz - mean2 * n1;
        float c0 = (Sz - mean2 * visible) - c1;
        float dotv = istd2 * (hi * c1 + lo * c0);
        float xn = sqrtf(fmaxf(sum_sp2, 1e-6f));
        float yn = sqrtf(fmaxf(sum_rb2, 1e-6f));
        float agree = fminf(fmaxf(dotv / fmaxf(xn * yn, 1e-6f), -1.f), 1.f);
        float gate = 1.f / (1.f + expf(-(agree - 0.15f) * 4.f));
        pcoef = 0.35f * (0.05f + 0.5f * gate);
    }

    // ---- Phase 3: speech + pause scores (L3-hot reloads) + trace_ctx write (moved here)
    float v[EPT], ps[EPT];
#pragma unroll
    for (int i = 0; i < EPT; i++) {
        int t = i * NTH + tid;
        float c = crow[t];
        float pf = (t == T - 1) ? 1.f : crow[t + 1];
        float4 tr = trow[t];
        float m = (t < L) ? 1.f : 0.f;
        o_tc[t] = make_float4(tr.x * m, tr.y * m, tr.z * m, tr.w * m);
        float vv = 0.f, pp = 0.f;
        if (t < L) {
            float z1 = (tr.y - mean1) * istd1;
            float z3 = (tr.w - mean3) * istd3;
            vv = expf(log1pf(fmaxf(durr[i], 0.f)) + 0.45f * z1 + 0.3f * z3 + 0.2f * pf);
            float z0 = (tr.x - mean0) * istd0;
            float rbv = (tr.z - mean2) * istd2;
            float spv = lo + c * (hi - lo);
            pp = expf(1.1f * z0 + 1.5f * rbv + pcoef * spv);
        }
        v[i] = vv; ps[i] = pp;
        if (lane == 0)  s_vL[wid][i] = vv;
        if (lane == 63) s_vR[wid][i] = vv;
    }
    __syncthreads();                                   // B2 (edges visible)

    // ---- Phase 3b: smooth3 in place + sum (single-barrier reduce)
    float a1 = 0.f;
#pragma unroll
    for (int i = 0; i < EPT; i++) {
        int t = i * NTH + tid;
        float vl = __shfl_up(v[i], 1);
        if (lane == 0)
            vl = (wid > 0) ? s_vR[wid - 1][i] : ((i > 0) ? s_vR[NW - 1][i - 1] : 0.f);
        float vr = __shfl_down(v[i], 1);
        if (lane == 63)
            vr = (wid < NW - 1) ? s_vL[wid + 1][i] : ((i + 1 < EPT) ? s_vL[0][i + 1] : 0.f);
        float smv = 0.f;
        if (t < L) smv = (vl + v[i] + vr) * (1.f / 3.f);
        v[i] = smv; a1 += smv;
    }
    {
#pragma unroll
        for (int off = 32; off; off >>= 1) a1 += __shfl_xor(a1, off);
        if (lane == 0) s_red[wid] = a1;
    }
    __syncthreads();                                   // B3
    float tot1 = (lane < NW) ? s_red[lane] : 0.f;
#pragma unroll
    for (int off = 32; off; off >>= 1) tot1 += __shfl_xor(tot1, off);
    const float spe_scale = speech_budget / fmaxf(tot1, 1e-6f);

    // ---- Phase 4: radix select, 4 rounds x ONE barrier (per-wave redundant scan)
    unsigned pref = 0u, cmaskk = 0u;
    unsigned kk = (unsigned)kint;
    unsigned cnt_eq = 0u;
    int cur = 0;
#pragma unroll 1
    for (int r = 0; r < 4; r++) {
        const int shift = 24 - 8 * r;
#pragma unroll
        for (int i = 0; i < EPT; i++) {
            unsigned b = __float_as_uint(ps[i]);
            if ((b & cmaskk) == pref)
                atomicAdd(&s_hist[cur * (NW * 256) + wid * 256 + ((b >> shift) & 0xFFu)], 1u);
        }
        __syncthreads();                               // B4..B7
        // every wave scans all 16 copies redundantly
        unsigned bb = lane * 4;
        unsigned h0 = 0, h1 = 0, h2 = 0, h3 = 0;
#pragma unroll
        for (int w = 0; w < NW; w++) {
            int hb = cur * (NW * 256) + w * 256 + bb;
            h0 += s_hist[hb + 0]; h1 += s_hist[hb + 1];
            h2 += s_hist[hb + 2]; h3 += s_hist[hb + 3];
        }
        unsigned s = h0 + h1 + h2 + h3;
        unsigned vs = s;
#pragma unroll
        for (int off = 1; off < 64; off <<= 1) {
            unsigned u = __shfl_down(vs, off);
            if (lane + off < 64) vs += u;
        }
        unsigned vnext = __shfl_down(vs, 1);
        if (lane == 63) vnext = 0u;
        unsigned higher = vs - s;
        unsigned S3 = higher + h3;
        unsigned S2 = S3 + h2;
        unsigned S1 = S2 + h1;
        unsigned S0 = S1 + h0;
        unsigned sel = 0u, sub = 0u, top = 0u;
        bool found = false;
        if (S3 >= kk && vnext < kk)    { sel = bb + 3; sub = vnext; top = S3; found = true; }
        else if (S2 >= kk && S3 < kk)  { sel = bb + 2; sub = S3;    top = S2; found = true; }
        else if (S1 >= kk && S2 < kk)  { sel = bb + 1; sub = S2;    top = S1; found = true; }
        else if (S0 >= kk && S1 < kk)  { sel = bb + 0; sub = S1;    top = S0; found = true; }
        unsigned long long ball = __ballot(found);
        int src = __ffsll((unsigned long long)ball) - 1;
        sel = (unsigned)__shfl((int)sel, src);
        sub = (unsigned)__shfl((int)sub, src);
        top = (unsigned)__shfl((int)top, src);
        pref |= sel << shift;
        cmaskk |= 0xFFu << shift;
        kk -= sub;
        if (r == 3) cnt_eq = top - sub;
        if (r < 3) {   // clear own copy of the OTHER buffer (wave-local, no barrier)
            int hb = (cur ^ 1) * (NW * 256) + wid * 256 + lane * 4;
            s_hist[hb] = 0u; s_hist[hb + 1] = 0u; s_hist[hb + 2] = 0u; s_hist[hb + 3] = 0u;
        }
        cur ^= 1;
    }
    const unsigned thr_bits = pref;
    const unsigned keep_eq = kk;

    // ---- Phase 5: keep top-k; stable tie-break only if ties straddle the cut
    float accp = 0.f;
    if (cnt_eq == keep_eq) {
#pragma unroll
        for (int c = 0; c < EPT; c++) {
            unsigned b = __float_as_uint(ps[c]);
            float pv = (b >= thr_bits) ? ps[c] : 0.f;
            ps[c] = pv; accp += pv;
        }
    } else {
        unsigned carry_eq = 0u;
#pragma unroll
        for (int c = 0; c < EPT; c++) {
            unsigned b = __float_as_uint(ps[c]);
            bool eq = (b == thr_bits);
            unsigned long long bal = __ballot(eq);
            unsigned lpre = (unsigned)__popcll(bal & ((1ull << lane) - 1ull));
            unsigned wc = (unsigned)__popcll(bal);
            if (lane == 0) s_wu[wid] = wc;
            __syncthreads();
            unsigned woff = 0u, tot = 0u;
#pragma unroll
            for (int w = 0; w < NW; w++) { unsigned x = s_wu[w]; if (w < wid) woff += x; tot += x; }
            __syncthreads();
            unsigned rank = carry_eq + woff + lpre;
            bool keep = (b > thr_bits) || (eq && rank < keep_eq);
            float pv = keep ? ps[c] : 0.f;
            ps[c] = pv; accp += pv;
            carry_eq += tot;
        }
    }
    {
#pragma unroll
        for (int off = 32; off; off >>= 1) accp += __shfl_xor(accp, off);
        if (lane == 0) s_red[wid] = accp;
    }
    __syncthreads();                                   // B8
    float tot2 = (lane < NW) ? s_red[lane] : 0.f;
#pragma unroll
    for (int off = 32; off; off >>= 1) tot2 += __shfl_xor(tot2, off);
    const float pa_scale = pause_budget / fmaxf(tot2, 1e-6f);

    // ---- Phase 6: writes + wave scan + ONE barrier + redundant 128-partial scan
    const float inv_alloc = 1.f / fmaxf(speech_budget + pause_budget, 1e-6f);
#pragma unroll
    for (int c = 0; c < EPT; c++) {
        int t = c * NTH + tid;
        bool in = t < L;
        float spe = v[c] * spe_scale;
        float pae = ps[c] * pa_scale;
        o_spe[t] = spe;
        o_pae[t] = pae;
        o_al[t] = (spe + pae) * inv_alloc;
        float x = in ? (spe + pae - durr[c]) : 0.f;
#pragma unroll
        for (int off = 1; off < 64; off <<= 1) {
            float u = __shfl_up(x, off);
            if (lane >= off) x += u;
        }
        v[c] = x;                        // per-lane inclusive scan within wave
        if (lane == 63) s_part[c * NW + wid] = x;
    }
    __syncthreads();                                   // B9
    {
        // every wave scans the 128 wave-partials redundantly (2 per lane)
        float a = s_part[2 * lane], b = s_part[2 * lane + 1];
        float pair = a + b;
        float inc = pair;
#pragma unroll
        for (int off = 1; off < 64; off <<= 1) {
            float u = __shfl_up(inc, off);
            if (lane >= off) inc += u;
        }
        float excl = inc - pair;         // exclusive sum of pairs at this lane
#pragma unroll
        for (int c = 0; c < EPT; c++) {
            int t = c * NTH + tid;
            bool in = t < L;
            int p = c * NW + wid;
            float e  = __shfl(excl, p >> 1);
            float av = __shfl(a,    p >> 1);
            float off0 = e + ((p & 1) ? av : 0.f);
            float incl = off0 + v[c];
            o_pc[t] = in ? incl : 0.f;
            o_bk[t] = in ? fmaxf(incl, 0.f) : 0.f;
        }
    }

    if (tid == 0) {
        o_sb[row] = speech_budget;
        o_pb[row] = pause_budget;
        o_cf[row] = conf;
    }
}

extern "C" void kernel_launch(void* const* d_in, const int* in_sizes, int n_in,
                              void* d_out, int out_size, void* d_ws, size_t ws_size,
                              hipStream_t stream) {
    const float* dur   = (const float*)d_in[0];
    const float* stats = (const float*)d_in[1];
    const float* trace = (const float*)d_in[2];
    const float* mask  = (const float*)d_in[3];
    const float* cue   = (const float*)d_in[4];
    float* out = (float*)d_out;

    teacher_kernel<<<dim3(BATCH), dim3(NTH), 0, stream>>>(dur, stats, trace, mask, cue, out);
}